// Round 8
// baseline (474.912 us; speedup 1.0000x reference)
//
#include <hip/hip_runtime.h>
#include <math.h>

#define NN 100000
#define NE 1600000
#define EPSBN 1e-5f
#define NBUCK 391   // ceil(NN/256); bucket = dst>>8

// ---------------- bf16 helpers ----------------
static __device__ __forceinline__ unsigned short f2bf(float f) {
    unsigned int u = __float_as_uint(f);
    u += 0x7fffu + ((u >> 16) & 1u);   // round-to-nearest-even
    return (unsigned short)(u >> 16);
}
static __device__ __forceinline__ float bf2f(unsigned short s) {
    return __uint_as_float(((unsigned int)s) << 16);
}
static __device__ __forceinline__ void fma4(float4& a, float s, const float4& w) {
    a.x = fmaf(s, w.x, a.x); a.y = fmaf(s, w.y, a.y);
    a.z = fmaf(s, w.z, a.z); a.w = fmaf(s, w.w, a.w);
}
static __device__ __forceinline__ void fma2(float2& a, float s, const float2& w) {
    a.x = fmaf(s, w.x, a.x); a.y = fmaf(s, w.y, a.y);
}

// ---------------- CSR build ----------------
__global__ __launch_bounds__(512) void init_small(int* __restrict__ bkcnt,
                                                  int* __restrict__ bcur) {
    int t = threadIdx.x;
    bkcnt[t] = 0;
    bcur[t] = 0;
}

__global__ __launch_bounds__(256) void bucket_count(const int* __restrict__ dst,
                                                    int* __restrict__ bkcnt) {
    __shared__ int lh[NBUCK];
    int t = threadIdx.x;
    for (int b = t; b < NBUCK; b += 256) lh[b] = 0;
    __syncthreads();
    int e0 = blockIdx.x * 4096;
#pragma unroll
    for (int i = 0; i < 16; ++i) {
        int e = e0 + i * 256 + t;
        if (e < NE) atomicAdd(&lh[dst[e] >> 8], 1);
    }
    __syncthreads();
    for (int b = t; b < NBUCK; b += 256)
        if (lh[b]) atomicAdd(&bkcnt[b], lh[b]);
}

__global__ __launch_bounds__(512) void scan2(const int* __restrict__ bkcnt,
                                             int* __restrict__ bb0) {
    __shared__ int sh[512];
    int t = threadIdx.x;
    int val = (t < NBUCK) ? bkcnt[t] : 0;
    sh[t] = val;
    __syncthreads();
    for (int off = 1; off < 512; off <<= 1) {
        int x = (t >= off) ? sh[t - off] : 0;
        __syncthreads();
        sh[t] += x;
        __syncthreads();
    }
    bb0[t] = sh[t] - val;  // exclusive; bb0[NBUCK] == NE
}

// chunk = 16384 edges/block -> per-(block,bucket) runs avg ~42 edges (168 B)
__global__ __launch_bounds__(256) void bin_kernel(const int* __restrict__ src,
                                                  const int* __restrict__ dst,
                                                  const int* __restrict__ bb0,
                                                  int* __restrict__ bcur,
                                                  unsigned int* __restrict__ bucketed) {
    __shared__ int lh[NBUCK];
    __shared__ int lbase[NBUCK];
    __shared__ int lcur[NBUCK];
    int t = threadIdx.x;
    for (int b = t; b < NBUCK; b += 256) lh[b] = 0;
    __syncthreads();
    int e0 = blockIdx.x * 16384;
#pragma unroll
    for (int i = 0; i < 64; ++i) {
        int e = e0 + i * 256 + t;
        if (e < NE) atomicAdd(&lh[dst[e] >> 8], 1);
    }
    __syncthreads();
    for (int b = t; b < NBUCK; b += 256) {
        lbase[b] = bb0[b] + atomicAdd(&bcur[b], lh[b]);
        lcur[b] = 0;
    }
    __syncthreads();
#pragma unroll
    for (int i = 0; i < 64; ++i) {
        int e = e0 + i * 256 + t;
        if (e < NE) {
            int d = dst[e], s = src[e];
            int b = d >> 8;
            int pos = lbase[b] + atomicAdd(&lcur[b], 1);
            bucketed[pos] = (unsigned int)s | ((unsigned int)(d & 255) << 24);
        }
    }
}

__global__ __launch_bounds__(256) void fine_scatter_fused(const unsigned int* __restrict__ bucketed,
                                                          const int* __restrict__ bb0,
                                                          int* __restrict__ row_start,
                                                          float* __restrict__ dinv,
                                                          int* __restrict__ sorted_src) {
    __shared__ int hist[256];
    __shared__ int sc[256];
    __shared__ int rsl[256];
    __shared__ int lcur[256];
    int b = blockIdx.x, t = threadIdx.x;
    hist[t] = 0; lcur[t] = 0;
    __syncthreads();
    int e0 = bb0[b], e1 = bb0[b + 1];
    for (int e = e0 + t; e < e1; e += 256)
        atomicAdd(&hist[bucketed[e] >> 24], 1);
    __syncthreads();
    int val = hist[t];
    sc[t] = val;
    __syncthreads();
    for (int off = 1; off < 256; off <<= 1) {
        int x = (t >= off) ? sc[t - off] : 0;
        __syncthreads();
        sc[t] += x;
        __syncthreads();
    }
    int ex = sc[t] - val;
    int node = b * 256 + t;
    if (node < NN) {
        row_start[node] = e0 + ex;
        dinv[node] = rsqrtf(1.0f + (float)val);
    }
    if (node == NN) row_start[NN] = NE;
    rsl[t] = e0 + ex;
    __syncthreads();
    for (int e = e0 + t; e < e1; e += 256) {
        unsigned int p = bucketed[e];
        int dl = (int)(p >> 24);
        int pos = rsl[dl] + atomicAdd(&lcur[dl], 1);
        sorted_src[pos] = (int)(p & 0xFFFFFFu);
    }
}

// ---------------- GEMMs: reg-blocked 4x4, W staged in LDS ------
// layer 1: fp32 x input
__global__ __launch_bounds__(256) void gemm_128_64_v3(const float* __restrict__ x,
                                                      const float* __restrict__ W,
                                                      const float* __restrict__ dinv,
                                                      unsigned short* __restrict__ hs) {
    __shared__ float xs[64][132];
    __shared__ float ws[128][64];
    int tid = threadIdx.x;
    int bn = blockIdx.x * 64;
    for (int id = tid; id < 2048; id += 256) {
        int r = id >> 4, c4 = id & 15;
        *(float4*)&ws[r][c4 * 4] = *(const float4*)(W + r * 64 + c4 * 4);
    }
    for (int id = tid; id < 64 * 33; id += 256) {
        int r = id / 33, c4 = id - r * 33;
        int n = bn + r; if (n >= NN) n = NN - 1;
        float4 v = make_float4(0.f, 0.f, 0.f, 0.f);
        if (c4 < 32) v = *(const float4*)(x + (size_t)n * 128 + c4 * 4);
        *(float4*)&xs[r][c4 * 4] = v;
    }
    __syncthreads();
    int tn = tid >> 4, tf = tid & 15;
    int f0 = tf * 4;
    float4 acc[4] = {{0,0,0,0},{0,0,0,0},{0,0,0,0},{0,0,0,0}};
#pragma unroll 2
    for (int k = 0; k < 128; k += 4) {
        float4 w0 = *(const float4*)&ws[k + 0][f0];
        float4 w1 = *(const float4*)&ws[k + 1][f0];
        float4 w2 = *(const float4*)&ws[k + 2][f0];
        float4 w3 = *(const float4*)&ws[k + 3][f0];
#pragma unroll
        for (int i = 0; i < 4; ++i) {
            float4 xa = *(const float4*)&xs[tn * 4 + i][k];
            fma4(acc[i], xa.x, w0); fma4(acc[i], xa.y, w1);
            fma4(acc[i], xa.z, w2); fma4(acc[i], xa.w, w3);
        }
    }
#pragma unroll
    for (int i = 0; i < 4; ++i) {
        int n = bn + tn * 4 + i;
        if (n < NN) {
            float di = dinv[n];
            ushort4 u;
            u.x = f2bf(acc[i].x * di); u.y = f2bf(acc[i].y * di);
            u.z = f2bf(acc[i].z * di); u.w = f2bf(acc[i].w * di);
            *(ushort4*)(hs + (size_t)n * 64 + f0) = u;
        }
    }
}

// layers 2: bf16 activation input
__global__ __launch_bounds__(256) void gemm_64_64_bf(const unsigned short* __restrict__ xbf,
                                                     const float* __restrict__ W,
                                                     const float* __restrict__ dinv,
                                                     unsigned short* __restrict__ hs) {
    __shared__ float xs[64][68];
    __shared__ float ws[64][64];
    int tid = threadIdx.x;
    int bn = blockIdx.x * 64;
    for (int id = tid; id < 1024; id += 256) {
        int r = id >> 4, c4 = id & 15;
        *(float4*)&ws[r][c4 * 4] = *(const float4*)(W + r * 64 + c4 * 4);
    }
    for (int id = tid; id < 64 * 16; id += 256) {
        int r = id >> 4, c4 = id & 15;
        int n = bn + r; if (n >= NN) n = NN - 1;
        ushort4 u = *(const ushort4*)(xbf + (size_t)n * 64 + c4 * 4);
        float4 v; v.x = bf2f(u.x); v.y = bf2f(u.y); v.z = bf2f(u.z); v.w = bf2f(u.w);
        *(float4*)&xs[r][c4 * 4] = v;
    }
    __syncthreads();
    int tn = tid >> 4, tf = tid & 15;
    int f0 = tf * 4;
    float4 acc[4] = {{0,0,0,0},{0,0,0,0},{0,0,0,0},{0,0,0,0}};
#pragma unroll 2
    for (int k = 0; k < 64; k += 4) {
        float4 w0 = *(const float4*)&ws[k + 0][f0];
        float4 w1 = *(const float4*)&ws[k + 1][f0];
        float4 w2 = *(const float4*)&ws[k + 2][f0];
        float4 w3 = *(const float4*)&ws[k + 3][f0];
#pragma unroll
        for (int i = 0; i < 4; ++i) {
            float4 xa = *(const float4*)&xs[tn * 4 + i][k];
            fma4(acc[i], xa.x, w0); fma4(acc[i], xa.y, w1);
            fma4(acc[i], xa.z, w2); fma4(acc[i], xa.w, w3);
        }
    }
#pragma unroll
    for (int i = 0; i < 4; ++i) {
        int n = bn + tn * 4 + i;
        if (n < NN) {
            float di = dinv[n];
            ushort4 u;
            u.x = f2bf(acc[i].x * di); u.y = f2bf(acc[i].y * di);
            u.z = f2bf(acc[i].z * di); u.w = f2bf(acc[i].w * di);
            *(ushort4*)(hs + (size_t)n * 64 + f0) = u;
        }
    }
}

// layer 3: bf16 activation input, 16-wide out
__global__ __launch_bounds__(256) void gemm_64_16_bf(const unsigned short* __restrict__ xbf,
                                                     const float* __restrict__ W,
                                                     const float* __restrict__ dinv,
                                                     unsigned short* __restrict__ hs) {
    __shared__ float xs[128][68];
    __shared__ float ws[64][16];
    int tid = threadIdx.x;
    int bn = blockIdx.x * 128;
    for (int id = tid; id < 256; id += 256) {
        int r = id >> 2, c4 = id & 3;
        *(float4*)&ws[r][c4 * 4] = *(const float4*)(W + r * 16 + c4 * 4);
    }
    for (int id = tid; id < 128 * 16; id += 256) {
        int r = id >> 4, c4 = id & 15;
        int n = bn + r; if (n >= NN) n = NN - 1;
        ushort4 u = *(const ushort4*)(xbf + (size_t)n * 64 + c4 * 4);
        float4 v; v.x = bf2f(u.x); v.y = bf2f(u.y); v.z = bf2f(u.z); v.w = bf2f(u.w);
        *(float4*)&xs[r][c4 * 4] = v;
    }
    __syncthreads();
    int tn = tid >> 3, tf = tid & 7;
    int f0 = tf * 2;
    float2 acc[4] = {{0,0},{0,0},{0,0},{0,0}};
#pragma unroll 2
    for (int k = 0; k < 64; k += 4) {
        float2 w0 = *(const float2*)&ws[k + 0][f0];
        float2 w1 = *(const float2*)&ws[k + 1][f0];
        float2 w2 = *(const float2*)&ws[k + 2][f0];
        float2 w3 = *(const float2*)&ws[k + 3][f0];
#pragma unroll
        for (int i = 0; i < 4; ++i) {
            float4 xa = *(const float4*)&xs[tn * 4 + i][k];
            fma2(acc[i], xa.x, w0); fma2(acc[i], xa.y, w1);
            fma2(acc[i], xa.z, w2); fma2(acc[i], xa.w, w3);
        }
    }
#pragma unroll
    for (int i = 0; i < 4; ++i) {
        int n = bn + tn * 4 + i;
        if (n < NN) {
            float di = dinv[n];
            ushort2 u;
            u.x = f2bf(acc[i].x * di); u.y = f2bf(acc[i].y * di);
            *(ushort2*)(hs + (size_t)n * 16 + f0) = u;
        }
    }
}

// ---------------- CSR aggregation v3: lane=feature, 16 independent chains ----
// wave = 1 dst row; per 16-edge burst issue all gathers back-to-back (MLP).
// Guards are wave-uniform (nbb is uniform) -> scalar-branch, no divergence.
__global__ __launch_bounds__(256) void csr_agg64_v3(const int* __restrict__ rs,
                                                    const int* __restrict__ ss,
                                                    const unsigned short* __restrict__ hs,
                                                    const float* __restrict__ dinv,
                                                    const float* __restrict__ b,
                                                    const float* __restrict__ g,
                                                    const float* __restrict__ be,
                                                    const float* __restrict__ m,
                                                    const float* __restrict__ v,
                                                    unsigned short* __restrict__ outbf) {
    int lane = threadIdx.x & 63;
    int r = blockIdx.x * 4 + (threadIdx.x >> 6);
    int e0 = rs[r], e1 = rs[r + 1];
    float a0 = bf2f(hs[(size_t)r * 64 + lane]);  // self loop
    float a1 = 0.f, a2 = 0.f, a3 = 0.f, a4 = 0.f, a5 = 0.f, a6 = 0.f, a7 = 0.f;
    float a8 = 0.f, a9 = 0.f, a10 = 0.f, a11 = 0.f, a12 = 0.f, a13 = 0.f, a14 = 0.f, a15 = 0.f;
    for (int base = e0; base < e1; base += 64) {
        int nbb = e1 - base; if (nbb > 64) nbb = 64;
        int sidx = (lane < nbb) ? ss[base + lane] : 0;
        for (int j = 0; j < nbb; j += 16) {
#define GATH(K, ACC) if (j + K < nbb) { \
    int s_ = __shfl(sidx, j + K); \
    ACC += bf2f(hs[(size_t)s_ * 64 + lane]); }
            GATH(0, a0)  GATH(1, a1)  GATH(2, a2)  GATH(3, a3)
            GATH(4, a4)  GATH(5, a5)  GATH(6, a6)  GATH(7, a7)
            GATH(8, a8)  GATH(9, a9)  GATH(10, a10) GATH(11, a11)
            GATH(12, a12) GATH(13, a13) GATH(14, a14) GATH(15, a15)
#undef GATH
        }
    }
    float acc = ((a0 + a1) + (a2 + a3)) + ((a4 + a5) + (a6 + a7))
              + ((a8 + a9) + (a10 + a11)) + ((a12 + a13) + (a14 + a15));
    float h = dinv[r] * acc + b[lane];
    h = g[lane] * (h - m[lane]) * rsqrtf(v[lane] + EPSBN) + be[lane];
    outbf[(size_t)r * 64 + lane] = f2bf(fmaxf(h, 0.f));
}

// final layer: 8 groups of 8 lanes; lane loads ushort2 (2 feats); f32 sigmoid out
__global__ __launch_bounds__(256) void csr_agg16_v2(const int* __restrict__ rs,
                                                    const int* __restrict__ ss,
                                                    const unsigned short* __restrict__ hs,
                                                    const float* __restrict__ dinv,
                                                    const float* __restrict__ b,
                                                    float* __restrict__ out) {
    int lane = threadIdx.x & 63;
    int r = blockIdx.x * 4 + (threadIdx.x >> 6);
    int grp = lane >> 3, fl = lane & 7;
    int e0 = rs[r], e1 = rs[r + 1];
    float2 a0 = {0,0}, a1 = {0,0};
    if (grp == 0) {
        ushort2 u = *(const ushort2*)(hs + (size_t)r * 16 + fl * 2);
        a0.x = bf2f(u.x); a0.y = bf2f(u.y);
    }
    int jj = e0;
    for (; jj + 16 <= e1; jj += 16) {
        int s0 = ss[jj + grp];
        int s1 = ss[jj + 8 + grp];
        ushort2 u0 = *(const ushort2*)(hs + (size_t)s0 * 16 + fl * 2);
        ushort2 u1 = *(const ushort2*)(hs + (size_t)s1 * 16 + fl * 2);
        a0.x += bf2f(u0.x); a0.y += bf2f(u0.y);
        a1.x += bf2f(u1.x); a1.y += bf2f(u1.y);
    }
    for (; jj < e1; jj += 8) {
        int idx = jj + grp;
        if (idx < e1) {
            int s = ss[idx];
            ushort2 u = *(const ushort2*)(hs + (size_t)s * 16 + fl * 2);
            a1.x += bf2f(u.x); a1.y += bf2f(u.y);
        }
    }
    a0.x += a1.x; a0.y += a1.y;
    a0.x += __shfl_xor(a0.x, 8);  a0.y += __shfl_xor(a0.y, 8);
    a0.x += __shfl_xor(a0.x, 16); a0.y += __shfl_xor(a0.y, 16);
    a0.x += __shfl_xor(a0.x, 32); a0.y += __shfl_xor(a0.y, 32);
    if (grp == 0) {
        float di = dinv[r];
        float hx = di * a0.x + b[fl * 2];
        float hy = di * a0.y + b[fl * 2 + 1];
        float2 o;
        o.x = 1.0f / (1.0f + expf(-hx));
        o.y = 1.0f / (1.0f + expf(-hy));
        *(float2*)(out + (size_t)r * 16 + fl * 2) = o;
    }
}

extern "C" void kernel_launch(void* const* d_in, const int* in_sizes, int n_in,
                              void* d_out, int out_size, void* d_ws, size_t ws_size,
                              hipStream_t stream) {
    const float* x   = (const float*)d_in[0];
    const int*   ei  = (const int*)d_in[1];   // [2, E]: src = ei, dst = ei + NE
    const float* W1  = (const float*)d_in[2];
    const float* b1  = (const float*)d_in[3];
    const float* W2  = (const float*)d_in[4];
    const float* b2  = (const float*)d_in[5];
    const float* W3  = (const float*)d_in[6];
    const float* b3  = (const float*)d_in[7];
    const float* g1  = (const float*)d_in[8];
    const float* be1 = (const float*)d_in[9];
    const float* m1  = (const float*)d_in[10];
    const float* v1  = (const float*)d_in[11];
    const float* g2  = (const float*)d_in[12];
    const float* be2 = (const float*)d_in[13];
    const float* m2  = (const float*)d_in[14];
    const float* v2  = (const float*)d_in[15];
    float* out = (float*)d_out;

    const int* srcp = ei;
    const int* dstp = ei + NE;

    // workspace layout
    float* dinv = (float*)d_ws;                                   // NN f32
    unsigned short* Abf = (unsigned short*)(dinv + NN);           // NN*64 bf16 activations
    unsigned short* Bh  = Abf + (size_t)NN * 64;                  // NN*64 bf16 hs
    int* row_start  = (int*)(Bh + (size_t)NN * 64);               // NN+1
    int* bkcnt      = row_start + NN + 2;                         // 512
    int* bb0        = bkcnt + 512;                                // 512
    int* bcur       = bb0 + 512;                                  // 512
    int* sorted_src = bcur + 512;                                 // NE
    unsigned int* bucketed = (unsigned int*)(sorted_src + NE);    // NE

    dim3 blk(256);
    int gCNT  = (NE + 4095) / 4096;    // 391
    int gBIN  = (NE + 16383) / 16384;  // 98
    int gG1   = (NN + 63) / 64;        // 1563
    int gG3   = (NN + 127) / 128;      // 782
    int gA    = NN / 4;                // 25000

    // CSR build
    init_small<<<1, 512, 0, stream>>>(bkcnt, bcur);
    bucket_count<<<gCNT, blk, 0, stream>>>(dstp, bkcnt);
    scan2<<<1, 512, 0, stream>>>(bkcnt, bb0);
    bin_kernel<<<gBIN, blk, 0, stream>>>(srcp, dstp, bb0, bcur, bucketed);
    fine_scatter_fused<<<NBUCK, blk, 0, stream>>>(bucketed, bb0, row_start, dinv, sorted_src);

    // layer 1
    gemm_128_64_v3<<<gG1, blk, 0, stream>>>(x, W1, dinv, Bh);
    csr_agg64_v3<<<gA, blk, 0, stream>>>(row_start, sorted_src, Bh, dinv,
                                         b1, g1, be1, m1, v1, Abf);
    // layer 2
    gemm_64_64_bf<<<gG1, blk, 0, stream>>>(Abf, W2, dinv, Bh);
    csr_agg64_v3<<<gA, blk, 0, stream>>>(row_start, sorted_src, Bh, dinv,
                                         b2, g2, be2, m2, v2, Abf);
    // layer 3
    gemm_64_16_bf<<<gG3, blk, 0, stream>>>(Abf, W3, dinv, Bh);
    csr_agg16_v2<<<gA, blk, 0, stream>>>(row_start, sorted_src, Bh, dinv, b3, out);
}

// Round 9
// 376.545 us; speedup vs baseline: 1.2612x; 1.2612x over previous
//
#include <hip/hip_runtime.h>
#include <math.h>

#define NN 100000
#define NE 1600000
#define EPSBN 1e-5f
#define NBUCK 391   // ceil(NN/256); bucket = dst>>8

// ---------------- bf16 helpers ----------------
static __device__ __forceinline__ unsigned short f2bf(float f) {
    unsigned int u = __float_as_uint(f);
    u += 0x7fffu + ((u >> 16) & 1u);   // round-to-nearest-even
    return (unsigned short)(u >> 16);
}
static __device__ __forceinline__ float bf2f(unsigned short s) {
    return __uint_as_float(((unsigned int)s) << 16);
}
static __device__ __forceinline__ void fma4(float4& a, float s, const float4& w) {
    a.x = fmaf(s, w.x, a.x); a.y = fmaf(s, w.y, a.y);
    a.z = fmaf(s, w.z, a.z); a.w = fmaf(s, w.w, a.w);
}
static __device__ __forceinline__ void fma2(float2& a, float s, const float2& w) {
    a.x = fmaf(s, w.x, a.x); a.y = fmaf(s, w.y, a.y);
}

// ---------------- CSR build ----------------
__global__ __launch_bounds__(512) void init_small(int* __restrict__ bkcnt,
                                                  int* __restrict__ bcur) {
    int t = threadIdx.x;
    bkcnt[t] = 0;
    bcur[t] = 0;
}

__global__ __launch_bounds__(256) void bucket_count(const int* __restrict__ dst,
                                                    int* __restrict__ bkcnt) {
    __shared__ int lh[NBUCK];
    int t = threadIdx.x;
    for (int b = t; b < NBUCK; b += 256) lh[b] = 0;
    __syncthreads();
    int e0 = blockIdx.x * 4096;
#pragma unroll
    for (int i = 0; i < 16; ++i) {
        int e = e0 + i * 256 + t;
        if (e < NE) atomicAdd(&lh[dst[e] >> 8], 1);
    }
    __syncthreads();
    for (int b = t; b < NBUCK; b += 256)
        if (lh[b]) atomicAdd(&bkcnt[b], lh[b]);
}

__global__ __launch_bounds__(512) void scan2(const int* __restrict__ bkcnt,
                                             int* __restrict__ bb0) {
    __shared__ int sh[512];
    int t = threadIdx.x;
    int val = (t < NBUCK) ? bkcnt[t] : 0;
    sh[t] = val;
    __syncthreads();
    for (int off = 1; off < 512; off <<= 1) {
        int x = (t >= off) ? sh[t - off] : 0;
        __syncthreads();
        sh[t] += x;
        __syncthreads();
    }
    bb0[t] = sh[t] - val;  // exclusive; bb0[NBUCK] == NE
}

__global__ __launch_bounds__(256) void bin_kernel(const int* __restrict__ src,
                                                  const int* __restrict__ dst,
                                                  const int* __restrict__ bb0,
                                                  int* __restrict__ bcur,
                                                  unsigned int* __restrict__ bucketed) {
    __shared__ int lh[NBUCK];
    __shared__ int lbase[NBUCK];
    __shared__ int lcur[NBUCK];
    int t = threadIdx.x;
    for (int b = t; b < NBUCK; b += 256) lh[b] = 0;
    __syncthreads();
    int e0 = blockIdx.x * 4096;
#pragma unroll
    for (int i = 0; i < 16; ++i) {
        int e = e0 + i * 256 + t;
        if (e < NE) atomicAdd(&lh[dst[e] >> 8], 1);
    }
    __syncthreads();
    for (int b = t; b < NBUCK; b += 256) {
        lbase[b] = bb0[b] + atomicAdd(&bcur[b], lh[b]);
        lcur[b] = 0;
    }
    __syncthreads();
#pragma unroll
    for (int i = 0; i < 16; ++i) {
        int e = e0 + i * 256 + t;
        if (e < NE) {
            int d = dst[e], s = src[e];
            int b = d >> 8;
            int pos = lbase[b] + atomicAdd(&lcur[b], 1);
            bucketed[pos] = (unsigned int)s | ((unsigned int)(d & 255) << 24);
        }
    }
}

__global__ __launch_bounds__(256) void fine_scatter_fused(const unsigned int* __restrict__ bucketed,
                                                          const int* __restrict__ bb0,
                                                          int* __restrict__ row_start,
                                                          float* __restrict__ dinv,
                                                          int* __restrict__ sorted_src) {
    __shared__ int hist[256];
    __shared__ int sc[256];
    __shared__ int rsl[256];
    __shared__ int lcur[256];
    int b = blockIdx.x, t = threadIdx.x;
    hist[t] = 0; lcur[t] = 0;
    __syncthreads();
    int e0 = bb0[b], e1 = bb0[b + 1];
    for (int e = e0 + t; e < e1; e += 256)
        atomicAdd(&hist[bucketed[e] >> 24], 1);
    __syncthreads();
    int val = hist[t];
    sc[t] = val;
    __syncthreads();
    for (int off = 1; off < 256; off <<= 1) {
        int x = (t >= off) ? sc[t - off] : 0;
        __syncthreads();
        sc[t] += x;
        __syncthreads();
    }
    int ex = sc[t] - val;
    int node = b * 256 + t;
    if (node < NN) {
        row_start[node] = e0 + ex;
        dinv[node] = rsqrtf(1.0f + (float)val);
    }
    if (node == NN) row_start[NN] = NE;
    rsl[t] = e0 + ex;
    __syncthreads();
    for (int e = e0 + t; e < e1; e += 256) {
        unsigned int p = bucketed[e];
        int dl = (int)(p >> 24);
        int pos = rsl[dl] + atomicAdd(&lcur[dl], 1);
        sorted_src[pos] = (int)(p & 0xFFFFFFu);
    }
}

// ---------------- GEMMs: reg-blocked 4x4, W staged in LDS ------
// layer 1: fp32 x input
__global__ __launch_bounds__(256) void gemm_128_64_v3(const float* __restrict__ x,
                                                      const float* __restrict__ W,
                                                      const float* __restrict__ dinv,
                                                      unsigned short* __restrict__ hs) {
    __shared__ float xs[64][132];
    __shared__ float ws[128][64];
    int tid = threadIdx.x;
    int bn = blockIdx.x * 64;
    for (int id = tid; id < 2048; id += 256) {
        int r = id >> 4, c4 = id & 15;
        *(float4*)&ws[r][c4 * 4] = *(const float4*)(W + r * 64 + c4 * 4);
    }
    for (int id = tid; id < 64 * 33; id += 256) {
        int r = id / 33, c4 = id - r * 33;
        int n = bn + r; if (n >= NN) n = NN - 1;
        float4 v = make_float4(0.f, 0.f, 0.f, 0.f);
        if (c4 < 32) v = *(const float4*)(x + (size_t)n * 128 + c4 * 4);
        *(float4*)&xs[r][c4 * 4] = v;
    }
    __syncthreads();
    int tn = tid >> 4, tf = tid & 15;
    int f0 = tf * 4;
    float4 acc[4] = {{0,0,0,0},{0,0,0,0},{0,0,0,0},{0,0,0,0}};
#pragma unroll 2
    for (int k = 0; k < 128; k += 4) {
        float4 w0 = *(const float4*)&ws[k + 0][f0];
        float4 w1 = *(const float4*)&ws[k + 1][f0];
        float4 w2 = *(const float4*)&ws[k + 2][f0];
        float4 w3 = *(const float4*)&ws[k + 3][f0];
#pragma unroll
        for (int i = 0; i < 4; ++i) {
            float4 xa = *(const float4*)&xs[tn * 4 + i][k];
            fma4(acc[i], xa.x, w0); fma4(acc[i], xa.y, w1);
            fma4(acc[i], xa.z, w2); fma4(acc[i], xa.w, w3);
        }
    }
#pragma unroll
    for (int i = 0; i < 4; ++i) {
        int n = bn + tn * 4 + i;
        if (n < NN) {
            float di = dinv[n];
            ushort4 u;
            u.x = f2bf(acc[i].x * di); u.y = f2bf(acc[i].y * di);
            u.z = f2bf(acc[i].z * di); u.w = f2bf(acc[i].w * di);
            *(ushort4*)(hs + (size_t)n * 64 + f0) = u;
        }
    }
}

// layer 2: bf16 activation input
__global__ __launch_bounds__(256) void gemm_64_64_bf(const unsigned short* __restrict__ xbf,
                                                     const float* __restrict__ W,
                                                     const float* __restrict__ dinv,
                                                     unsigned short* __restrict__ hs) {
    __shared__ float xs[64][68];
    __shared__ float ws[64][64];
    int tid = threadIdx.x;
    int bn = blockIdx.x * 64;
    for (int id = tid; id < 1024; id += 256) {
        int r = id >> 4, c4 = id & 15;
        *(float4*)&ws[r][c4 * 4] = *(const float4*)(W + r * 64 + c4 * 4);
    }
    for (int id = tid; id < 64 * 16; id += 256) {
        int r = id >> 4, c4 = id & 15;
        int n = bn + r; if (n >= NN) n = NN - 1;
        ushort4 u = *(const ushort4*)(xbf + (size_t)n * 64 + c4 * 4);
        float4 v; v.x = bf2f(u.x); v.y = bf2f(u.y); v.z = bf2f(u.z); v.w = bf2f(u.w);
        *(float4*)&xs[r][c4 * 4] = v;
    }
    __syncthreads();
    int tn = tid >> 4, tf = tid & 15;
    int f0 = tf * 4;
    float4 acc[4] = {{0,0,0,0},{0,0,0,0},{0,0,0,0},{0,0,0,0}};
#pragma unroll 2
    for (int k = 0; k < 64; k += 4) {
        float4 w0 = *(const float4*)&ws[k + 0][f0];
        float4 w1 = *(const float4*)&ws[k + 1][f0];
        float4 w2 = *(const float4*)&ws[k + 2][f0];
        float4 w3 = *(const float4*)&ws[k + 3][f0];
#pragma unroll
        for (int i = 0; i < 4; ++i) {
            float4 xa = *(const float4*)&xs[tn * 4 + i][k];
            fma4(acc[i], xa.x, w0); fma4(acc[i], xa.y, w1);
            fma4(acc[i], xa.z, w2); fma4(acc[i], xa.w, w3);
        }
    }
#pragma unroll
    for (int i = 0; i < 4; ++i) {
        int n = bn + tn * 4 + i;
        if (n < NN) {
            float di = dinv[n];
            ushort4 u;
            u.x = f2bf(acc[i].x * di); u.y = f2bf(acc[i].y * di);
            u.z = f2bf(acc[i].z * di); u.w = f2bf(acc[i].w * di);
            *(ushort4*)(hs + (size_t)n * 64 + f0) = u;
        }
    }
}

// layer 3: bf16 activation input, 16-wide out
__global__ __launch_bounds__(256) void gemm_64_16_bf(const unsigned short* __restrict__ xbf,
                                                     const float* __restrict__ W,
                                                     const float* __restrict__ dinv,
                                                     unsigned short* __restrict__ hs) {
    __shared__ float xs[128][68];
    __shared__ float ws[64][16];
    int tid = threadIdx.x;
    int bn = blockIdx.x * 128;
    for (int id = tid; id < 256; id += 256) {
        int r = id >> 2, c4 = id & 3;
        *(float4*)&ws[r][c4 * 4] = *(const float4*)(W + r * 16 + c4 * 4);
    }
    for (int id = tid; id < 128 * 16; id += 256) {
        int r = id >> 4, c4 = id & 15;
        int n = bn + r; if (n >= NN) n = NN - 1;
        ushort4 u = *(const ushort4*)(xbf + (size_t)n * 64 + c4 * 4);
        float4 v; v.x = bf2f(u.x); v.y = bf2f(u.y); v.z = bf2f(u.z); v.w = bf2f(u.w);
        *(float4*)&xs[r][c4 * 4] = v;
    }
    __syncthreads();
    int tn = tid >> 3, tf = tid & 7;
    int f0 = tf * 2;
    float2 acc[4] = {{0,0},{0,0},{0,0},{0,0}};
#pragma unroll 2
    for (int k = 0; k < 64; k += 4) {
        float2 w0 = *(const float2*)&ws[k + 0][f0];
        float2 w1 = *(const float2*)&ws[k + 1][f0];
        float2 w2 = *(const float2*)&ws[k + 2][f0];
        float2 w3 = *(const float2*)&ws[k + 3][f0];
#pragma unroll
        for (int i = 0; i < 4; ++i) {
            float4 xa = *(const float4*)&xs[tn * 4 + i][k];
            fma2(acc[i], xa.x, w0); fma2(acc[i], xa.y, w1);
            fma2(acc[i], xa.z, w2); fma2(acc[i], xa.w, w3);
        }
    }
#pragma unroll
    for (int i = 0; i < 4; ++i) {
        int n = bn + tn * 4 + i;
        if (n < NN) {
            float di = dinv[n];
            ushort2 u;
            u.x = f2bf(acc[i].x * di); u.y = f2bf(acc[i].y * di);
            *(ushort2*)(hs + (size_t)n * 16 + f0) = u;
        }
    }
}

// ---------------- CSR aggregation v4: lane=feature, straight-line 8-bursts,
// readlane-scalarized indices -> saddr gathers, SALU does addressing ----------
__global__ __launch_bounds__(256) void csr_agg64_v4(const int* __restrict__ rs,
                                                    const int* __restrict__ ss,
                                                    const unsigned short* __restrict__ hs,
                                                    const float* __restrict__ dinv,
                                                    const float* __restrict__ b,
                                                    const float* __restrict__ g,
                                                    const float* __restrict__ be,
                                                    const float* __restrict__ m,
                                                    const float* __restrict__ v,
                                                    unsigned short* __restrict__ outbf) {
    int lane = threadIdx.x & 63;
    int r = blockIdx.x * 4 + (threadIdx.x >> 6);
    int e0 = rs[r], e1 = rs[r + 1];
    float a0 = bf2f(hs[(size_t)r * 64 + lane]);  // self loop
    float a1 = 0.f, a2 = 0.f, a3 = 0.f, a4 = 0.f, a5 = 0.f, a6 = 0.f, a7 = 0.f;
    for (int base = e0; base < e1; base += 64) {
        int nb = e1 - base; if (nb > 64) nb = 64;
        int sidx = (lane < nb) ? ss[base + lane] : 0;
        int j = 0;
        for (; j + 8 <= nb; j += 8) {   // straight-line burst: no branches between loads
            int s0 = __builtin_amdgcn_readlane(sidx, j + 0);
            int s1 = __builtin_amdgcn_readlane(sidx, j + 1);
            int s2 = __builtin_amdgcn_readlane(sidx, j + 2);
            int s3 = __builtin_amdgcn_readlane(sidx, j + 3);
            int s4 = __builtin_amdgcn_readlane(sidx, j + 4);
            int s5 = __builtin_amdgcn_readlane(sidx, j + 5);
            int s6 = __builtin_amdgcn_readlane(sidx, j + 6);
            int s7 = __builtin_amdgcn_readlane(sidx, j + 7);
            float c0 = bf2f(hs[(size_t)s0 * 64 + lane]);
            float c1 = bf2f(hs[(size_t)s1 * 64 + lane]);
            float c2 = bf2f(hs[(size_t)s2 * 64 + lane]);
            float c3 = bf2f(hs[(size_t)s3 * 64 + lane]);
            float c4 = bf2f(hs[(size_t)s4 * 64 + lane]);
            float c5 = bf2f(hs[(size_t)s5 * 64 + lane]);
            float c6 = bf2f(hs[(size_t)s6 * 64 + lane]);
            float c7 = bf2f(hs[(size_t)s7 * 64 + lane]);
            a0 += c0; a1 += c1; a2 += c2; a3 += c3;
            a4 += c4; a5 += c5; a6 += c6; a7 += c7;
        }
        for (; j < nb; ++j) {
            int s_ = __builtin_amdgcn_readlane(sidx, j);
            a0 += bf2f(hs[(size_t)s_ * 64 + lane]);
        }
    }
    float acc = ((a0 + a1) + (a2 + a3)) + ((a4 + a5) + (a6 + a7));
    float h = dinv[r] * acc + b[lane];
    h = g[lane] * (h - m[lane]) * rsqrtf(v[lane] + EPSBN) + be[lane];
    outbf[(size_t)r * 64 + lane] = f2bf(fmaxf(h, 0.f));
}

// final layer: 8 groups of 8 lanes; lane loads ushort2 (2 feats); f32 sigmoid out
__global__ __launch_bounds__(256) void csr_agg16_v2(const int* __restrict__ rs,
                                                    const int* __restrict__ ss,
                                                    const unsigned short* __restrict__ hs,
                                                    const float* __restrict__ dinv,
                                                    const float* __restrict__ b,
                                                    float* __restrict__ out) {
    int lane = threadIdx.x & 63;
    int r = blockIdx.x * 4 + (threadIdx.x >> 6);
    int grp = lane >> 3, fl = lane & 7;
    int e0 = rs[r], e1 = rs[r + 1];
    float2 a0 = {0,0}, a1 = {0,0};
    if (grp == 0) {
        ushort2 u = *(const ushort2*)(hs + (size_t)r * 16 + fl * 2);
        a0.x = bf2f(u.x); a0.y = bf2f(u.y);
    }
    int jj = e0;
    for (; jj + 16 <= e1; jj += 16) {
        int s0 = ss[jj + grp];
        int s1 = ss[jj + 8 + grp];
        ushort2 u0 = *(const ushort2*)(hs + (size_t)s0 * 16 + fl * 2);
        ushort2 u1 = *(const ushort2*)(hs + (size_t)s1 * 16 + fl * 2);
        a0.x += bf2f(u0.x); a0.y += bf2f(u0.y);
        a1.x += bf2f(u1.x); a1.y += bf2f(u1.y);
    }
    for (; jj < e1; jj += 8) {
        int idx = jj + grp;
        if (idx < e1) {
            int s = ss[idx];
            ushort2 u = *(const ushort2*)(hs + (size_t)s * 16 + fl * 2);
            a1.x += bf2f(u.x); a1.y += bf2f(u.y);
        }
    }
    a0.x += a1.x; a0.y += a1.y;
    a0.x += __shfl_xor(a0.x, 8);  a0.y += __shfl_xor(a0.y, 8);
    a0.x += __shfl_xor(a0.x, 16); a0.y += __shfl_xor(a0.y, 16);
    a0.x += __shfl_xor(a0.x, 32); a0.y += __shfl_xor(a0.y, 32);
    if (grp == 0) {
        float di = dinv[r];
        float hx = di * a0.x + b[fl * 2];
        float hy = di * a0.y + b[fl * 2 + 1];
        float2 o;
        o.x = 1.0f / (1.0f + expf(-hx));
        o.y = 1.0f / (1.0f + expf(-hy));
        *(float2*)(out + (size_t)r * 16 + fl * 2) = o;
    }
}

extern "C" void kernel_launch(void* const* d_in, const int* in_sizes, int n_in,
                              void* d_out, int out_size, void* d_ws, size_t ws_size,
                              hipStream_t stream) {
    const float* x   = (const float*)d_in[0];
    const int*   ei  = (const int*)d_in[1];   // [2, E]: src = ei, dst = ei + NE
    const float* W1  = (const float*)d_in[2];
    const float* b1  = (const float*)d_in[3];
    const float* W2  = (const float*)d_in[4];
    const float* b2  = (const float*)d_in[5];
    const float* W3  = (const float*)d_in[6];
    const float* b3  = (const float*)d_in[7];
    const float* g1  = (const float*)d_in[8];
    const float* be1 = (const float*)d_in[9];
    const float* m1  = (const float*)d_in[10];
    const float* v1  = (const float*)d_in[11];
    const float* g2  = (const float*)d_in[12];
    const float* be2 = (const float*)d_in[13];
    const float* m2  = (const float*)d_in[14];
    const float* v2  = (const float*)d_in[15];
    float* out = (float*)d_out;

    const int* srcp = ei;
    const int* dstp = ei + NE;

    // workspace layout
    float* dinv = (float*)d_ws;                                   // NN f32
    unsigned short* Abf = (unsigned short*)(dinv + NN);           // NN*64 bf16 activations
    unsigned short* Bh  = Abf + (size_t)NN * 64;                  // NN*64 bf16 hs
    int* row_start  = (int*)(Bh + (size_t)NN * 64);               // NN+1
    int* bkcnt      = row_start + NN + 2;                         // 512
    int* bb0        = bkcnt + 512;                                // 512
    int* bcur       = bb0 + 512;                                  // 512
    int* sorted_src = bcur + 512;                                 // NE
    unsigned int* bucketed = (unsigned int*)(sorted_src + NE);    // NE

    dim3 blk(256);
    int gCNT  = (NE + 4095) / 4096;    // 391
    int gBIN  = (NE + 4095) / 4096;    // 391
    int gG1   = (NN + 63) / 64;        // 1563
    int gG3   = (NN + 127) / 128;      // 782
    int gA    = NN / 4;                // 25000

    // CSR build
    init_small<<<1, 512, 0, stream>>>(bkcnt, bcur);
    bucket_count<<<gCNT, blk, 0, stream>>>(dstp, bkcnt);
    scan2<<<1, 512, 0, stream>>>(bkcnt, bb0);
    bin_kernel<<<gBIN, blk, 0, stream>>>(srcp, dstp, bb0, bcur, bucketed);
    fine_scatter_fused<<<NBUCK, blk, 0, stream>>>(bucketed, bb0, row_start, dinv, sorted_src);

    // layer 1
    gemm_128_64_v3<<<gG1, blk, 0, stream>>>(x, W1, dinv, Bh);
    csr_agg64_v4<<<gA, blk, 0, stream>>>(row_start, sorted_src, Bh, dinv,
                                         b1, g1, be1, m1, v1, Abf);
    // layer 2
    gemm_64_64_bf<<<gG1, blk, 0, stream>>>(Abf, W2, dinv, Bh);
    csr_agg64_v4<<<gA, blk, 0, stream>>>(row_start, sorted_src, Bh, dinv,
                                         b2, g2, be2, m2, v2, Abf);
    // layer 3
    gemm_64_16_bf<<<gG3, blk, 0, stream>>>(Abf, W3, dinv, Bh);
    csr_agg16_v2<<<gA, blk, 0, stream>>>(row_start, sorted_src, Bh, dinv, b3, out);
}